// Round 1
// baseline (267.638 us; speedup 1.0000x reference)
//
#include <hip/hip_runtime.h>
#include <stdint.h>

// MLP_tcnn: x(524288x64) -> [W0 64x128 relu] -> [W1..W4 128x128 relu] -> [W5 128x16] + bias
// Strategy: per-block 128-sample tile; per layer compute H_next^T = W^T * H^T with
// mfma_f32_16x16x32_bf16.  A = W^T (rows = out-feature, contiguous in-features),
// B = H^T read from sample-major LDS rows, C written back sample-major as b64.
// Weight images pre-converted+pre-transposed+pre-swizzled into d_ws by prep kernel,
// staged per layer via global_load_lds (16B).  XOR chunk swizzle -> uniform banks.

typedef __bf16 bf16x8 __attribute__((ext_vector_type(8)));
typedef __bf16 bf16x4 __attribute__((ext_vector_type(4)));
typedef float  floatx4 __attribute__((ext_vector_type(4)));

#define GAS __attribute__((address_space(1)))
#define LAS __attribute__((address_space(3)))

constexpr int NS   = 524288;   // samples
constexpr int TILE = 128;      // samples per block
constexpr int NBLK = NS / TILE;

// weight image offsets/counts in 16B chunks inside d_ws
// L0: 128 rows x 8 chunks (K=64); L1-4: 128 x 16; L5: 16 x 16
constexpr int WTOT = 9472;     // total chunks = 151552 bytes

__global__ void prep_weights(const float* __restrict__ W0, const float* __restrict__ W1,
                             const float* __restrict__ W2, const float* __restrict__ W3,
                             const float* __restrict__ W4, const float* __restrict__ W5,
                             bf16x8* __restrict__ ws) {
  int gid = blockIdx.x * blockDim.x + threadIdx.x;
  if (gid >= WTOT) return;
  const float* Wsrc; int nout, cpr, base;
  if (gid < 1024)      { Wsrc = W0; nout = 128; cpr = 8;  base = 0;    }
  else if (gid < 3072) { Wsrc = W1; nout = 128; cpr = 16; base = 1024; }
  else if (gid < 5120) { Wsrc = W2; nout = 128; cpr = 16; base = 3072; }
  else if (gid < 7168) { Wsrc = W3; nout = 128; cpr = 16; base = 5120; }
  else if (gid < 9216) { Wsrc = W4; nout = 128; cpr = 16; base = 7168; }
  else                 { Wsrc = W5; nout = 16;  cpr = 16; base = 9216; }
  int id = gid - base;
  int n  = id / cpr;          // out-feature = row of W^T image
  int p  = id % cpr;          // physical chunk slot in row
  int c  = p ^ (n & 7);       // logical k-chunk stored at this slot (XOR swizzle)
  bf16x8 v;
#pragma unroll
  for (int j = 0; j < 8; ++j)
    v[j] = (__bf16)Wsrc[(8 * c + j) * nout + n];   // W^T[n][8c+j] = W[8c+j][n]
  ws[gid] = v;
}

__device__ __forceinline__ void stage_w(const bf16x8* __restrict__ src, bf16x8* dst,
                                        int nchunks, int w, int lane) {
  int per  = nchunks >> 2;       // chunks per wave
  int base = w * per;
  for (int i = 0; i < per; i += 64) {
    __builtin_amdgcn_global_load_lds(
        (const GAS void*)(src + base + i + lane),   // per-lane global src
        (LAS void*)(dst + base + i),                // wave-uniform LDS base (+lane*16 in HW)
        16, 0, 0);
  }
}

__device__ __forceinline__ void zero_acc(floatx4 acc[4][4]) {
  floatx4 z = {0.f, 0.f, 0.f, 0.f};
#pragma unroll
  for (int i = 0; i < 4; ++i)
#pragma unroll
    for (int j = 0; j < 4; ++j) acc[i][j] = z;
}

// one 128-out x 128-sample (per-block) layer; each wave does a 64x64 quadrant.
// KT = K/32, CPR = chunks per W-image row (K/8).
template <int KT, int CPR>
__device__ __forceinline__ void layer_mm(const bf16x8* Wb, const bf16x8* Hb,
                                         floatx4 acc[4][4], int m_base, int n_base,
                                         int l15, int g) {
#pragma unroll
  for (int kt = 0; kt < KT; ++kt) {
    const int cx = (kt * 4 + g) ^ (l15 & 7);
    bf16x8 a[4], b[4];
#pragma unroll
    for (int i = 0; i < 4; ++i) a[i] = Wb[(m_base + 16 * i + l15) * CPR + cx];
#pragma unroll
    for (int i = 0; i < 4; ++i) b[i] = Hb[(n_base + 16 * i + l15) * 16 + cx];
#pragma unroll
    for (int ot = 0; ot < 4; ++ot)
#pragma unroll
      for (int nt = 0; nt < 4; ++nt)
        acc[ot][nt] = __builtin_amdgcn_mfma_f32_16x16x32_bf16(a[ot], b[nt], acc[ot][nt], 0, 0, 0);
  }
}

// C-frag (col=sample=lane&15, rows = 4g..4g+3 out-features) -> relu -> bf16 -> H (sample-major)
__device__ __forceinline__ void write_h(bf16x4* H8, const floatx4 acc[4][4],
                                        int m_base, int n_base, int l15, int g) {
#pragma unroll
  for (int ot = 0; ot < 4; ++ot) {
    int ob    = m_base + 16 * ot + 4 * g;                        // out-feature base (4-aligned)
    int phys8 = (((ob >> 3) ^ (l15 & 7)) << 1) | ((ob >> 2) & 1);
#pragma unroll
    for (int nt = 0; nt < 4; ++nt) {
      int s = n_base + 16 * nt + l15;                            // sample row
      floatx4 v = acc[ot][nt];
      bf16x4 h;
      h[0] = (__bf16)fmaxf(v[0], 0.0f);
      h[1] = (__bf16)fmaxf(v[1], 0.0f);
      h[2] = (__bf16)fmaxf(v[2], 0.0f);
      h[3] = (__bf16)fmaxf(v[3], 0.0f);
      H8[s * 32 + phys8] = h;
    }
  }
}

__global__ void __launch_bounds__(256) mlp_kernel(const float* __restrict__ x,
                                                  const float* __restrict__ bias,
                                                  const bf16x8* __restrict__ wimg,
                                                  float* __restrict__ out) {
  __shared__ bf16x8 Hbuf[TILE * 16];   // 32KB: sample-major rows, 16 chunks, XOR-swizzled
  __shared__ bf16x8 Wbuf[2048];        // 32KB: current layer's W^T image

  const int t    = threadIdx.x;
  const int lane = t & 63;
  const int w    = t >> 6;
  const int l15  = lane & 15;
  const int g    = lane >> 4;
  const int m_base = (w & 1) * 64;     // out-feature quadrant
  const int n_base = (w >> 1) * 64;    // sample quadrant
  const int tile = blockIdx.x;

  constexpr int WOFF[6] = {0, 1024, 3072, 5120, 7168, 9216};
  constexpr int WCNT[6] = {1024, 2048, 2048, 2048, 2048, 256};

  // stage W0 image (async)
  stage_w(wimg + WOFF[0], Wbuf, WCNT[0], w, lane);

  // stage x tile -> Hbuf (fp32 -> bf16), one 16B chunk (8 feats of one sample) per iter
  const float* xt = x + (size_t)tile * TILE * 64;
#pragma unroll
  for (int i = 0; i < 4; ++i) {
    int f2 = t + 256 * i;              // chunk id 0..1023
    int s = f2 >> 3, c = f2 & 7;
    const floatx4* src = (const floatx4*)(xt + f2 * 8);
    floatx4 lo = src[0], hi = src[1];
    bf16x8 v;
    v[0] = (__bf16)lo[0]; v[1] = (__bf16)lo[1]; v[2] = (__bf16)lo[2]; v[3] = (__bf16)lo[3];
    v[4] = (__bf16)hi[0]; v[5] = (__bf16)hi[1]; v[6] = (__bf16)hi[2]; v[7] = (__bf16)hi[3];
    Hbuf[s * 16 + (c ^ (s & 7))] = v;
  }
  __syncthreads();   // drains global_load_lds (vmcnt) + LDS writes

  floatx4 acc[4][4];

  // ---- layer 0: K=64 ----
  zero_acc(acc);
  layer_mm<2, 8>(Wbuf, Hbuf, acc, m_base, n_base, l15, g);
  __syncthreads();                                   // all Wbuf/Hbuf reads done
  stage_w(wimg + WOFF[1], Wbuf, WCNT[1], w, lane);   // async stage W1
  write_h((bf16x4*)Hbuf, acc, m_base, n_base, l15, g);
  __syncthreads();

  // ---- layers 1..4: K=128 ----
#pragma unroll
  for (int l = 1; l <= 4; ++l) {
    zero_acc(acc);
    layer_mm<4, 16>(Wbuf, Hbuf, acc, m_base, n_base, l15, g);
    __syncthreads();
    stage_w(wimg + WOFF[l + 1], Wbuf, WCNT[l + 1], w, lane);
    write_h((bf16x4*)Hbuf, acc, m_base, n_base, l15, g);
    __syncthreads();
  }

  // ---- layer 5: M=16, K=128, no relu, + bias, store fp32 ----
  floatx4 a5[2];
  {
    floatx4 z = {0.f, 0.f, 0.f, 0.f};
    a5[0] = z; a5[1] = z;
  }
  const int n5 = w * 32;               // each wave: 32 samples, all 16 out-features
#pragma unroll
  for (int kt = 0; kt < 4; ++kt) {
    int cx = (kt * 4 + g) ^ (l15 & 7);
    bf16x8 a = Wbuf[l15 * 16 + cx];    // W5^T row = out-feature l15
#pragma unroll
    for (int nt = 0; nt < 2; ++nt) {
      bf16x8 b = Hbuf[(n5 + 16 * nt + l15) * 16 + cx];
      a5[nt] = __builtin_amdgcn_mfma_f32_16x16x32_bf16(a, b, a5[nt], 0, 0, 0);
    }
  }
  floatx4 bv = *(const floatx4*)(bias + 4 * g);
  floatx4* outv = (floatx4*)out;
#pragma unroll
  for (int nt = 0; nt < 2; ++nt) {
    int s = tile * TILE + n5 + 16 * nt + l15;
    outv[s * 4 + g] = a5[nt] + bv;     // wave's 8 stores cover 1KB contiguous
  }
}

extern "C" void kernel_launch(void* const* d_in, const int* in_sizes, int n_in,
                              void* d_out, int out_size, void* d_ws, size_t ws_size,
                              hipStream_t stream) {
  (void)in_sizes; (void)n_in; (void)out_size; (void)ws_size;
  const float* x    = (const float*)d_in[0];
  const float* W0   = (const float*)d_in[1];
  const float* W1   = (const float*)d_in[2];
  const float* W2   = (const float*)d_in[3];
  const float* W3   = (const float*)d_in[4];
  const float* W4   = (const float*)d_in[5];
  const float* W5   = (const float*)d_in[6];
  const float* bias = (const float*)d_in[7];
  bf16x8* ws = (bf16x8*)d_ws;   // needs 151552 B

  prep_weights<<<(WTOT + 255) / 256, 256, 0, stream>>>(W0, W1, W2, W3, W4, W5, ws);
  mlp_kernel<<<NBLK, 256, 0, stream>>>(x, bias, (const bf16x8*)ws, (float*)d_out);
}